// Round 17
// baseline (95.460 us; speedup 1.0000x reference)
//
#include <hip/hip_runtime.h>
#include <math.h>

// Soft silhouette renderer — 16x16 tiles, 16-wave blocks (R17).
// verts: (4, 778, 3) f32   faces: (1538, 3) i32   out: (4, 320, 320) f32
//
// Verified-exact math core (R4, absmax 0.0):
//   area2 = fma(dx1, dy2, -round(dy1*dx2)) — matches the reference
//   evaluator's contraction; degenerate faces (sgn=0 -> 1/8 veil, i1==i2
//   sliver -> sigma=1/2 ridge) fall out of the generic edge code.
//
// R16 decomposition of the 88us bench: ~40us harness ws-poison fill
// (uncontrollable) + ~8us overhead + ~1.5us prep + ~38us render. Render =
// ~17.5us j-loop VALU + ~13.6us staging L2 (6400 blocks x 1538 faces x
// 48B = 470MB at 34.5TB/s) + barriers/latency. This round: 16x16-px tiles
// -> staging /4 (118MB), paid with +24% band faces (wider reach).
// BLOCK=1024 (16 waves) = 4 pixel-quadrants x 4-way face split keeps the
// critical-path split R6->R13 proved necessary; 2 blocks/CU = same 32
// waves/CU occupancy.
//   wave = 4*slice + quadrant; lane owns pixel (quadrant, lane&63);
//   slice s processes faces j = s, s+4, ...; tot(pix) = prod over slices.
// Keeps: prep kernel, product domain, cover-count fold (applied by slice-0
// waves: once per pixel), per-pixel m>T shortcut, single-edge fast path,
// per-lane live gate + ballot-break, index compaction, alive-vote before
// staging, T_CUT=12, ACC_CUT=e^-13.
//
// Error budget vs 2e-2 tolerance (measured 0.00390625 = one bf16 ulp =
// harness quantization floor since R5): cull skip <= 1538*e^-12 = 9.4e-3
// worst-case; covering shortcut <=2e-5/face absolute on tot; saturation
// cut 2.3e-6; product rounding ~1e-4.

#define IMG_S 320
#define N_FACES 1538
#define N_VERTS 778
#define N_BATCH 4
#define FP 1600            // padded face stride in ws
#define TILE 16
#define BLOCK 1024
#define NSLICE 4
#define CHUNK_F 768        // faces per chunk (2 chunks: 768 + 770)
#define INV_SIGMA 100.0f
#define T_CUT 12.0f
#define ACC_CUT_P 2.2603294e-6f    // e^-13, product-domain saturation
#define LOG2_1EM6 -19.9315686f     // log2(1e-6)

__global__ __launch_bounds__(256)
void prep_faces(const float* __restrict__ verts,
                const int* __restrict__ faces,
                float4* __restrict__ gE0,
                float4* __restrict__ gE1,
                float4* __restrict__ gE2)
{
    const int f = blockIdx.x * 256 + threadIdx.x;
    const int b = blockIdx.z;
    if (f >= N_FACES) return;

    const float* vb = verts + (size_t)b * N_VERTS * 3;
    const int i0 = faces[f * 3 + 0];
    const int i1 = faces[f * 3 + 1];
    const int i2 = faces[f * 3 + 2];
    const float x0 = vb[i0 * 3 + 0], y0 = -vb[i0 * 3 + 1];
    const float x1 = vb[i1 * 3 + 0], y1 = -vb[i1 * 3 + 1];
    const float x2 = vb[i2 * 3 + 0], y2 = -vb[i2 * 3 + 1];

    // VERIFIED-EXACT (R4): fma-contracted area2 — do not change.
    const float dx1 = x1 - x0, dy1 = y1 - y0;
    const float dx2 = x2 - x0, dy2 = y2 - y0;
    const float area2 = __builtin_fmaf(dx1, dy2, -__fmul_rn(dy1, dx2));
    const float sgn = (area2 > 0.0f) ? 1.0f : ((area2 < 0.0f) ? -1.0f : 0.0f);

    const size_t o = (size_t)b * FP + f;
    {   // edge v0 -> v1
        const float ex = x1 - x0, ey = y1 - y0;
        const float s = sgn * INV_SIGMA / (sqrtf(ex * ex + ey * ey) + 1e-8f);
        gE0[o] = make_float4(-s * ey, s * ex, s * (ey * x0 - ex * y0), 0.0f);
    }
    {   // edge v1 -> v2
        const float ex = x2 - x1, ey = y2 - y1;
        const float s = sgn * INV_SIGMA / (sqrtf(ex * ex + ey * ey) + 1e-8f);
        gE1[o] = make_float4(-s * ey, s * ex, s * (ey * x1 - ex * y1), 0.0f);
    }
    {   // edge v2 -> v0
        const float ex = x0 - x2, ey = y0 - y2;
        const float s = sgn * INV_SIGMA / (sqrtf(ex * ex + ey * ey) + 1e-8f);
        gE2[o] = make_float4(-s * ey, s * ex, s * (ey * x2 - ex * y2), 0.0f);
    }
}

__global__ __launch_bounds__(BLOCK)
void silhouette_ws(const float4* __restrict__ gE0,
                   const float4* __restrict__ gE1,
                   const float4* __restrict__ gE2,
                   float* __restrict__ out)
{
    __shared__ int sIdx[CHUNK_F + 8];
    __shared__ float sAcc[BLOCK];
    __shared__ int sCount;
    __shared__ int sAlive;
    __shared__ int sCover;

    const int t     = threadIdx.x;
    const int wave  = t >> 6;
    const int lane  = t & 63;
    const int slice = wave >> 2;      // 0..3: face-split slice
    const int quad  = wave & 3;       // 0..3: pixel quadrant
    const int pix   = quad * 64 + lane;        // 0..255 within 16x16 tile
    const int plx   = (quad & 1) * 8 + (lane & 7);
    const int ply   = (quad >> 1) * 8 + (lane >> 3);
    const int b     = blockIdx.z;
    const int gx    = blockIdx.x * TILE + plx;
    const int gy    = blockIdx.y * TILE + ply;

    const float w  = 2.0f / IMG_S;
    const float px = (gx + 0.5f) * w - 1.0f;
    const float py = (gy + 0.5f) * w - 1.0f;
    const float cx = (blockIdx.x * TILE + 8) * w - 1.0f;
    const float cy = (blockIdx.y * TILE + 8) * w - 1.0f;
    const float rr = 7.5f * w;        // half-extent of 16x16 pixel centers

    const float4* gb0 = gE0 + (size_t)b * FP;   // per-batch base
    const float4* gb1 = gE1 + (size_t)b * FP;
    const float4* gb2 = gE2 + (size_t)b * FP;

    float acc = 1.0f;   // product of (1-prob) over this slice's face subset
                        // (slice 0 also carries the cover factors)

    for (int c = 0; c < 2; ++c) {
        const int base = c * CHUNK_F;
        const int end  = (c == 0) ? CHUNK_F : N_FACES;

        sAcc[t] = acc;   // t = slice*256 + pix
        if (t == 0) { sCount = 0; sAlive = 0; sCover = 0; }
        __syncthreads();   // B1: resets + partials visible

        const float tot = sAcc[pix] * sAcc[pix + 256] * sAcc[pix + 512] * sAcc[pix + 768];
        const bool alive = (tot > ACC_CUT_P);
        if (alive) sAlive = 1;               // benign same-value race
        __syncthreads();   // B2: vote final — break BEFORE staging

        if (sAlive == 0) break;   // uniform: every pixel saturated

        // ---- staging: classify faces, compact band INDICES ----
        for (int fb = base; fb < end; fb += BLOCK) {
            const int fc = fb + t;
            const bool vald = (fc < end);
            const int fcc = vald ? fc : (end - 1);
            const float4 e0 = gb0[fcc];      // coalesced vector loads
            const float4 e1 = gb1[fcc];
            const float4 e2 = gb2[fcc];
            const float c0 = fmaf(e0.x, cx, fmaf(e0.y, cy, e0.z));
            const float c1 = fmaf(e1.x, cx, fmaf(e1.y, cy, e1.z));
            const float c2 = fmaf(e2.x, cx, fmaf(e2.y, cy, e2.z));
            const float r0 = rr * (fabsf(e0.x) + fabsf(e0.y));
            const float r1 = rr * (fabsf(e1.x) + fabsf(e1.y));
            const float r2 = rr * (fabsf(e2.x) + fabsf(e2.y));
            const float m_hi = fminf(c0 + r0, fminf(c1 + r1, c2 + r2));
            const float m_lo = fminf(c0 - r0, fminf(c1 - r1, c2 - r2));
            const bool isCov  = vald && (m_lo > T_CUT);
            const bool isBand = vald && !isCov && (m_hi > -T_CUT);

            const unsigned long long mb = __ballot(isBand);
            int wbase = 0;
            if (lane == 0) {
                const int nw = __popcll(mb);
                if (nw) wbase = atomicAdd(&sCount, nw);
            }
            wbase = __shfl(wbase, 0);
            if (isBand) {
                sIdx[wbase + __popcll(mb & ((1ull << lane) - 1ull))] = fc;
            }
            const unsigned long long mc = __ballot(isCov);
            if (lane == 0) {
                const int ncv = __popcll(mc);
                if (ncv) atomicAdd(&sCover, ncv);
            }
        }
        __syncthreads();   // B3: compaction + cover count final

        const float coverF = exp2f((float)sCover * LOG2_1EM6);
        bool live = alive && (acc * coverF > ACC_CUT_P);
        if (slice == 0) acc *= coverF;   // once per pixel (4 quads of slice 0)

        const int n = sCount;
        for (int j = slice; j < n; j += NSLICE) {
            if (__ballot(live) == 0ull) break;   // whole wave saturated
            int fj = sIdx[j];                    // 4B broadcast read
            fj = __builtin_amdgcn_readfirstlane(fj);
            const float4 e0 = gb0[fj];           // wave-uniform scalar loads
            const float4 e1 = gb1[fj];
            const float4 e2 = gb2[fj];
            const float xa = fmaf(e0.x, px, fmaf(e0.y, py, e0.z));
            const float xb = fmaf(e1.x, px, fmaf(e1.y, py, e1.z));
            const float xc = fmaf(e2.x, px, fmaf(e2.y, py, e2.z));
            const float m = fminf(xa, fminf(xb, xc));
            if (live && m > -T_CUT) {
                float f;
                if (m > T_CUT) {
                    f = 1e-6f;   // pixel-covering: ref clips prob at 1-1e-6
                } else {
                    const float mid = fmaxf(fminf(fmaxf(xa, xb), xc),
                                            fminf(xa, xb));   // median
                    if (mid > T_CUT) {
                        // single edge in band: f = sigma(-m) >= 6e-6
                        f = 1.0f - __builtin_amdgcn_rcpf(1.0f + __expf(-m));
                    } else {
                        const float da = 1.0f + __expf(-xa);
                        const float db = 1.0f + __expf(-xb);
                        const float dc = 1.0f + __expf(-xc);
                        f = 1.0f - __builtin_amdgcn_rcpf(da * db * dc);
                    }
                }
                acc *= f;
                live = (acc > ACC_CUT_P);
            }
        }

        __syncthreads();   // B4: j-loop index reads done before next chunk
    }

    // final reduction + output (loop exits are block-uniform)
    sAcc[t] = acc;
    __syncthreads();
    if (t < 256) {
        const float tot = sAcc[pix] * sAcc[pix + 256] * sAcc[pix + 512] * sAcc[pix + 768];
        out[(size_t)b * (IMG_S * IMG_S) + (size_t)gy * IMG_S + gx] = 1.0f - tot;
    }
}

extern "C" void kernel_launch(void* const* d_in, const int* in_sizes, int n_in,
                              void* d_out, int out_size, void* d_ws, size_t ws_size,
                              hipStream_t stream) {
    const float* verts = (const float*)d_in[0];
    const int* faces = (const int*)d_in[1];
    float* out = (float*)d_out;

    // ws layout: 3 arrays of float4[N_BATCH * FP]  (3 * 4*1600*16B = 307 KB)
    float4* gE0 = (float4*)d_ws;
    float4* gE1 = gE0 + (size_t)N_BATCH * FP;
    float4* gE2 = gE1 + (size_t)N_BATCH * FP;

    dim3 pgrid((N_FACES + 255) / 256, 1, N_BATCH);
    prep_faces<<<pgrid, 256, 0, stream>>>(verts, faces, gE0, gE1, gE2);

    dim3 grid(IMG_S / TILE, IMG_S / TILE, N_BATCH);
    silhouette_ws<<<grid, BLOCK, 0, stream>>>(gE0, gE1, gE2, out);
}

// Round 18
// 82.841 us; speedup vs baseline: 1.1523x; 1.1523x over previous
//
#include <hip/hip_runtime.h>
#include <math.h>

// Soft silhouette renderer — R18 = R16 + 2x-unrolled branchless j-loop.
// verts: (4, 778, 3) f32   faces: (1538, 3) i32   out: (4, 320, 320) f32
//
// Verified-exact math core (R4, absmax 0.0):
//   area2 = fma(dx1, dy2, -round(dy1*dx2)) — matches the reference
//   evaluator's contraction; degenerate faces (sgn=0 -> 1/8 veil, i1==i2
//   sliver -> sigma=1/2 ridge) fall out of the generic edge code.
//
// R17 post-mortem: 16x16/1024-thr regressed (44.5us, VALUBusy 33%) — the
// staging-L2 theory was wrong (12 TB/s << 34.5 ceiling); big blocks =
// coarse barriers + fewer blocks + more band faces. R16 structure stays.
// This round, j-loop only (the serial latency chain: ds_read idx ->
// readfirstlane -> 3x s_load ~200cyc per iteration, ballot blocking
// overlap):
//  * 2x EXPLICIT UNROLL: both iterations' indices + 6 float4 scalar loads
//    issued before any compute; ballot every 2 iterations.
//  * BRANCHLESS BODY: sIdx faces are never tile-covering (staging filters
//    them), so waves are mixed-lane and pay 3 exps anyway. Drop the
//    median / single-edge / covering branches:
//      f = fmax(1 - rcp((1+e^-xa)(1+e^-xb)(1+e^-xc)), 1e-6)
//    reproduces all three old paths within ~1e-7 (incl. ref's 1-1e-6
//    clip); m > -12 bounds exp inputs (no overflow).
// Keeps everything else from R16: 256-thr, 8x8 tiles, 2 chunks, alive-vote
// before staging, index ballot-scan compaction, cover-count fold,
// per-lane live gate, T_CUT=12, ACC_CUT=e^-13.
//
// Error budget vs 2e-2 tolerance (measured 0.00390625 = one bf16 ulp =
// harness quantization floor since R5): cull skip <= 1538*e^-12 = 9.4e-3
// worst-case; branchless factor ~1e-7/face; saturation cut 2.3e-6;
// product rounding ~1e-4.

#define IMG_S 320
#define N_FACES 1538
#define N_VERTS 778
#define N_BATCH 4
#define FP 1600            // padded face stride in ws
#define TILE 8
#define CHUNK_F 768        // faces per chunk (2 chunks: 768 + 770)
#define NWAVE 4
#define INV_SIGMA 100.0f
#define T_CUT 12.0f
#define ACC_CUT_P 2.2603294e-6f    // e^-13, product-domain saturation
#define LOG2_1EM6 -19.9315686f     // log2(1e-6)

__global__ __launch_bounds__(256)
void prep_faces(const float* __restrict__ verts,
                const int* __restrict__ faces,
                float4* __restrict__ gE0,
                float4* __restrict__ gE1,
                float4* __restrict__ gE2)
{
    const int f = blockIdx.x * 256 + threadIdx.x;
    const int b = blockIdx.z;
    if (f >= N_FACES) return;

    const float* vb = verts + (size_t)b * N_VERTS * 3;
    const int i0 = faces[f * 3 + 0];
    const int i1 = faces[f * 3 + 1];
    const int i2 = faces[f * 3 + 2];
    const float x0 = vb[i0 * 3 + 0], y0 = -vb[i0 * 3 + 1];
    const float x1 = vb[i1 * 3 + 0], y1 = -vb[i1 * 3 + 1];
    const float x2 = vb[i2 * 3 + 0], y2 = -vb[i2 * 3 + 1];

    // VERIFIED-EXACT (R4): fma-contracted area2 — do not change.
    const float dx1 = x1 - x0, dy1 = y1 - y0;
    const float dx2 = x2 - x0, dy2 = y2 - y0;
    const float area2 = __builtin_fmaf(dx1, dy2, -__fmul_rn(dy1, dx2));
    const float sgn = (area2 > 0.0f) ? 1.0f : ((area2 < 0.0f) ? -1.0f : 0.0f);

    const size_t o = (size_t)b * FP + f;
    {   // edge v0 -> v1
        const float ex = x1 - x0, ey = y1 - y0;
        const float s = sgn * INV_SIGMA / (sqrtf(ex * ex + ey * ey) + 1e-8f);
        gE0[o] = make_float4(-s * ey, s * ex, s * (ey * x0 - ex * y0), 0.0f);
    }
    {   // edge v1 -> v2
        const float ex = x2 - x1, ey = y2 - y1;
        const float s = sgn * INV_SIGMA / (sqrtf(ex * ex + ey * ey) + 1e-8f);
        gE1[o] = make_float4(-s * ey, s * ex, s * (ey * x1 - ex * y1), 0.0f);
    }
    {   // edge v2 -> v0
        const float ex = x0 - x2, ey = y0 - y2;
        const float s = sgn * INV_SIGMA / (sqrtf(ex * ex + ey * ey) + 1e-8f);
        gE2[o] = make_float4(-s * ey, s * ex, s * (ey * x2 - ex * y2), 0.0f);
    }
}

__global__ __launch_bounds__(256)
void silhouette_ws(const float4* __restrict__ gE0,
                   const float4* __restrict__ gE1,
                   const float4* __restrict__ gE2,
                   float* __restrict__ out)
{
    __shared__ int sIdx[CHUNK_F + 8];
    __shared__ float sAcc[256];
    __shared__ int sCount;
    __shared__ int sAlive;
    __shared__ int sCover;

    const int t    = threadIdx.x;
    const int wave = t >> 6;
    const int lane = t & 63;
    const int p    = t & 63;          // pixel id within 8x8 tile
    const int plx  = p & 7;
    const int ply  = p >> 3;
    const int b    = blockIdx.z;
    const int gx   = blockIdx.x * TILE + plx;
    const int gy   = blockIdx.y * TILE + ply;

    const float w  = 2.0f / IMG_S;
    const float px = (gx + 0.5f) * w - 1.0f;
    const float py = (gy + 0.5f) * w - 1.0f;
    const float cx = (blockIdx.x * TILE + 4) * w - 1.0f;
    const float cy = (blockIdx.y * TILE + 4) * w - 1.0f;
    const float rr = 3.5f * w;

    const float4* gb0 = gE0 + (size_t)b * FP;   // per-batch base
    const float4* gb1 = gE1 + (size_t)b * FP;
    const float4* gb2 = gE2 + (size_t)b * FP;

    float acc = 1.0f;   // product of (1-prob) over this wave's face subset
                        // (wave 0 also carries the cover factors)

    for (int c = 0; c < 2; ++c) {
        const int base = c * CHUNK_F;
        const int end  = (c == 0) ? CHUNK_F : N_FACES;

        sAcc[t] = acc;
        if (t == 0) { sCount = 0; sAlive = 0; sCover = 0; }
        __syncthreads();   // B1: resets + partials visible

        const float tot = sAcc[p] * sAcc[p + 64] * sAcc[p + 128] * sAcc[p + 192];
        const bool alive = (tot > ACC_CUT_P);
        if (alive) sAlive = 1;               // benign same-value race
        __syncthreads();   // B2: vote final — break BEFORE staging

        if (sAlive == 0) break;   // uniform: every pixel saturated

        // ---- staging: classify faces, compact band INDICES ----
        for (int fb = base; fb < end; fb += 256) {
            const int fc = fb + t;
            const bool vald = (fc < end);
            const int fcc = vald ? fc : (end - 1);
            const float4 e0 = gb0[fcc];      // coalesced vector loads
            const float4 e1 = gb1[fcc];
            const float4 e2 = gb2[fcc];
            const float c0 = fmaf(e0.x, cx, fmaf(e0.y, cy, e0.z));
            const float c1 = fmaf(e1.x, cx, fmaf(e1.y, cy, e1.z));
            const float c2 = fmaf(e2.x, cx, fmaf(e2.y, cy, e2.z));
            const float r0 = rr * (fabsf(e0.x) + fabsf(e0.y));
            const float r1 = rr * (fabsf(e1.x) + fabsf(e1.y));
            const float r2 = rr * (fabsf(e2.x) + fabsf(e2.y));
            const float m_hi = fminf(c0 + r0, fminf(c1 + r1, c2 + r2));
            const float m_lo = fminf(c0 - r0, fminf(c1 - r1, c2 - r2));
            const bool isCov  = vald && (m_lo > T_CUT);
            const bool isBand = vald && !isCov && (m_hi > -T_CUT);

            const unsigned long long mb = __ballot(isBand);
            int wbase = 0;
            if (lane == 0) {
                const int nw = __popcll(mb);
                if (nw) wbase = atomicAdd(&sCount, nw);
            }
            wbase = __shfl(wbase, 0);
            if (isBand) {
                sIdx[wbase + __popcll(mb & ((1ull << lane) - 1ull))] = fc;
            }
            const unsigned long long mc = __ballot(isCov);
            if (lane == 0) {
                const int ncv = __popcll(mc);
                if (ncv) atomicAdd(&sCover, ncv);
            }
        }
        __syncthreads();   // B3: compaction + cover count final

        const float coverF = exp2f((float)sCover * LOG2_1EM6);
        bool live = alive && (acc * coverF > ACC_CUT_P);
        if (wave == 0) acc *= coverF;

        const int n = sCount;
        int j = wave;
        while (j < n) {
            if (__ballot(live) == 0ull) break;   // whole wave saturated
            const int j1 = j + NWAVE;
            // issue both iterations' loads before any compute
            const int fj0 = __builtin_amdgcn_readfirstlane(sIdx[j]);
            const int fj1 = __builtin_amdgcn_readfirstlane(
                                sIdx[(j1 < n) ? j1 : j]);
            const float4 A0 = gb0[fj0], A1 = gb1[fj0], A2 = gb2[fj0];
            const float4 B0 = gb0[fj1], B1 = gb1[fj1], B2 = gb2[fj1];
            {   // iteration 0 — branchless band body
                const float xa = fmaf(A0.x, px, fmaf(A0.y, py, A0.z));
                const float xb = fmaf(A1.x, px, fmaf(A1.y, py, A1.z));
                const float xc = fmaf(A2.x, px, fmaf(A2.y, py, A2.z));
                const float m = fminf(xa, fminf(xb, xc));
                if (live && m > -T_CUT) {
                    const float da = 1.0f + __expf(-xa);
                    const float db = 1.0f + __expf(-xb);
                    const float dc = 1.0f + __expf(-xc);
                    const float f = fmaxf(
                        1.0f - __builtin_amdgcn_rcpf(da * db * dc), 1e-6f);
                    acc *= f;
                    live = (acc > ACC_CUT_P);
                }
            }
            if (j1 < n) {   // iteration 1
                const float xa = fmaf(B0.x, px, fmaf(B0.y, py, B0.z));
                const float xb = fmaf(B1.x, px, fmaf(B1.y, py, B1.z));
                const float xc = fmaf(B2.x, px, fmaf(B2.y, py, B2.z));
                const float m = fminf(xa, fminf(xb, xc));
                if (live && m > -T_CUT) {
                    const float da = 1.0f + __expf(-xa);
                    const float db = 1.0f + __expf(-xb);
                    const float dc = 1.0f + __expf(-xc);
                    const float f = fmaxf(
                        1.0f - __builtin_amdgcn_rcpf(da * db * dc), 1e-6f);
                    acc *= f;
                    live = (acc > ACC_CUT_P);
                }
            }
            j += 2 * NWAVE;
        }

        __syncthreads();   // B4: j-loop index reads done before next chunk
    }

    // final reduction + output (loop exits are block-uniform)
    sAcc[t] = acc;
    __syncthreads();
    if (t < 64) {
        const float tot = sAcc[p] * sAcc[p + 64] * sAcc[p + 128] * sAcc[p + 192];
        out[(size_t)b * (IMG_S * IMG_S) + (size_t)gy * IMG_S + gx] = 1.0f - tot;
    }
}

extern "C" void kernel_launch(void* const* d_in, const int* in_sizes, int n_in,
                              void* d_out, int out_size, void* d_ws, size_t ws_size,
                              hipStream_t stream) {
    const float* verts = (const float*)d_in[0];
    const int* faces = (const int*)d_in[1];
    float* out = (float*)d_out;

    // ws layout: 3 arrays of float4[N_BATCH * FP]  (3 * 4*1600*16B = 307 KB)
    float4* gE0 = (float4*)d_ws;
    float4* gE1 = gE0 + (size_t)N_BATCH * FP;
    float4* gE2 = gE1 + (size_t)N_BATCH * FP;

    dim3 pgrid((N_FACES + 255) / 256, 1, N_BATCH);
    prep_faces<<<pgrid, 256, 0, stream>>>(verts, faces, gE0, gE1, gE2);

    dim3 grid(IMG_S / TILE, IMG_S / TILE, N_BATCH);
    silhouette_ws<<<grid, 256, 0, stream>>>(gE0, gE1, gE2, out);
}